// Round 1
// baseline (532.098 us; speedup 1.0000x reference)
//
#include <hip/hip_runtime.h>
#include <hip/hip_bf16.h>
#include <stdint.h>

#define N_PTS 400000
#define K_TAPS 9
#define CIN 128
#define COUT 128
#define EPS_BN 1e-4f
#define LEAK 0.333f

typedef __bf16 bf16x8 __attribute__((ext_vector_type(8)));
typedef float floatx16 __attribute__((ext_vector_type(16)));

// ws layout (bytes):
//   [0, 294912)              packed W (bf16) in B-fragment order
//   [294912, 295424)         gsum[128]   (float)
//   [295424, 295936)         gsumsq[128] (float)
//   [295936, 296960)         ab[256]     (float: a[128], b[128])
//   -- Path A only --
//   [296960, 102696960)      feats_bf16 [N,128]
//   [102696960, 205096960)   prebn_bf16 [N,128]
#define PACKW_BYTES (K_TAPS * 8 * 4 * 64 * 8 * 2)  // 294912 (32768 B per tap)
#define SUMS_OFF PACKW_BYTES
#define SUMSQ_OFF (SUMS_OFF + 512)
#define AB_OFF (SUMSQ_OFF + 512)
#define FEATSB_OFF (AB_OFF + 1024)                        // 296960
#define PREBN_OFF (FEATSB_OFF + (size_t)N_PTS * CIN * 2)  // 102696960
#define WS_NEED_A (PREBN_OFF + (size_t)N_PTS * COUT * 2)  // 205096960

// round-to-nearest (half away) fp32 -> bf16, packed pair
__device__ inline unsigned int pack_bf16_rn(float lo, float hi) {
    unsigned int a = __float_as_uint(lo) + 0x8000u;
    unsigned int b = __float_as_uint(hi) + 0x8000u;
    return (a >> 16) | (b & 0xffff0000u);
}

// async global->LDS, 16B per lane. LDS dest is wave-uniform base + lane*16.
__device__ inline void gload_lds16(const void* g, void* l) {
    __builtin_amdgcn_global_load_lds(
        (const __attribute__((address_space(1))) unsigned int*)g,
        (__attribute__((address_space(3))) unsigned int*)l, 16, 0, 0);
}

__global__ void zero_sums_kernel(float* __restrict__ gsum) {
    gsum[threadIdx.x] = 0.0f;  // covers gsum[128] + gsumsq[128] (contiguous)
}

// fp32 feats -> bf16 (rn), 8 elems/thread
__global__ __launch_bounds__(256) void convert_feats_kernel(
    const float* __restrict__ f, __hip_bfloat16* __restrict__ o) {
    size_t i = ((size_t)blockIdx.x * 256 + threadIdx.x) * 8;
    const float4* f4 = (const float4*)(f + i);
    float4 a = f4[0], b = f4[1];
    uint4 v;
    v.x = pack_bf16_rn(a.x, a.y);
    v.y = pack_bf16_rn(a.z, a.w);
    v.z = pack_bf16_rn(b.x, b.y);
    v.w = pack_bf16_rn(b.z, b.w);
    *(uint4*)(o + i) = v;
}

// Pack W[k][ci][co] (fp32) into bf16 MFMA B-fragment order:
// packw[frag=((k*8+c)*4+t)][lane*8+j] = W[k][c*16 + (lane>>5)*8 + j][t*32 + (lane&31)]
__global__ void pack_w_kernel(const float* __restrict__ W,
                              __hip_bfloat16* __restrict__ pw) {
    int frag = blockIdx.x;  // 0..287
    int lane = threadIdx.x; // 0..63
    int t = frag & 3;
    int c = (frag >> 2) & 7;
    int k = frag >> 5;
    int n = lane & 31;
    int kk0 = (lane >> 5) * 8;
    const float* src = W + (size_t)k * CIN * COUT + (size_t)(c * 16 + kk0) * COUT + (t * 32 + n);
    __hip_bfloat16* dst = pw + (size_t)frag * 512 + lane * 8;
#pragma unroll
    for (int j = 0; j < 8; ++j) dst[j] = (__hip_bfloat16)src[(size_t)j * COUT];
}

// Stage one tap's packed W (32 KB) into LDS buffer buf via async global_load_lds.
// 8 waves x 4 chunks x (64 lanes x 16B) = 32 KB, linear layout.
__device__ inline void stage_tap(char* smem, const char* pwb, int k, int buf,
                                 int wave, int lane) {
    const char* g = pwb + (size_t)k * 32768;
    char* l = smem + buf * 32768;
#pragma unroll
    for (int i = 0; i < 4; ++i) {
        int chunk = i * 8 + wave;
        gload_lds16(g + (size_t)chunk * 1024 + (size_t)lane * 16, l + (size_t)chunk * 1024);
    }
}

// Main gather-GEMM. Grid: 1563 x 512. WG tile: 256 rows x 128 cout (8 waves).
// Wave w: rows [blk*256 + w*32, +32) x 128 cout via 4 n-tiles of 32x32x16 MFMA.
// A-frag: m=lane&31, k=(lane>>5)*8+j. B-frag mirror. (AMD 32x32 lane mappings.)
// W double-buffered in LDS (2x32KB); tap k+1 staged asynchronously (global_load_lds)
// while tap k computes; ONE barrier per tap (drain at barrier lands after the MFMAs).
template <bool GATHER_BF16, bool OUT_BF16>
__global__ __launch_bounds__(512, 4) void spconv_gemm_kernel(
    const void* __restrict__ feats_any,
    const __hip_bfloat16* __restrict__ packw,
    const int* __restrict__ neigh,
    void* __restrict__ out_any,
    float* __restrict__ gsum, float* __restrict__ gsumsq) {
    __shared__ __align__(16) char smem[65536];

    const int tid = threadIdx.x;
    const int wave = tid >> 6;
    const int lane = tid & 63;
    const int hj = lane >> 5;
    const int m = lane & 31;
    const int row = blockIdx.x * 256 + wave * 32 + m;
    const bool rvalid = (row < N_PTS);

    int nbr[K_TAPS];
#pragma unroll
    for (int k = 0; k < K_TAPS; ++k)
        nbr[k] = rvalid ? neigh[(size_t)row * K_TAPS + k] : N_PTS;

    floatx16 acc[4];
#pragma unroll
    for (int t = 0; t < 4; ++t)
#pragma unroll
        for (int r = 0; r < 16; ++r) acc[t][r] = 0.0f;

    const char* pwb = (const char*)packw;

    // prologue: stage tap 0 into buf 0 (drained by the syncthreads' vmcnt(0))
    stage_tap(smem, pwb, 0, 0, wave, lane);
    __syncthreads();

    int cur = 0;
#pragma unroll
    for (int k = 0; k < K_TAPS; ++k) {
        const int nb = nbr[k];
        const bool valid = (nb < N_PTS);
        const int safe = valid ? nb : 0;

        // Issue the 8 A-gather loads first (random rows: longest latency)...
        uint4 av[8];
        if (GATHER_BF16) {
            const uint4* arow =
                (const uint4*)((const __hip_bfloat16*)feats_any + (size_t)safe * CIN);
#pragma unroll
            for (int c = 0; c < 8; ++c) av[c] = arow[c * 2 + hj];
        } else {
            const float4* arow =
                (const float4*)((const float*)feats_any + (size_t)safe * CIN);
#pragma unroll
            for (int c = 0; c < 8; ++c) {
                float4 f0 = arow[c * 4 + hj * 2];
                float4 f1 = arow[c * 4 + hj * 2 + 1];
                av[c].x = pack_bf16_rn(f0.x, f0.y);
                av[c].y = pack_bf16_rn(f0.z, f0.w);
                av[c].z = pack_bf16_rn(f1.x, f1.y);
                av[c].w = pack_bf16_rn(f1.z, f1.w);
            }
        }

        // ...then the async stage of the NEXT tap into the other LDS buffer
        // (latency hidden under this tap's MFMAs; drained at the barrier below).
        if (k + 1 < K_TAPS) stage_tap(smem, pwb, k + 1, cur ^ 1, wave, lane);

        if (!valid) {
#pragma unroll
            for (int c = 0; c < 8; ++c) { av[c].x = 0u; av[c].y = 0u; av[c].z = 0u; av[c].w = 0u; }
        }

        const char* bbase = smem + cur * 32768;
        __builtin_amdgcn_s_setprio(1);
#pragma unroll
        for (int c = 0; c < 8; ++c) {
            bf16x8 afrag = __builtin_bit_cast(bf16x8, av[c]);
#pragma unroll
            for (int t = 0; t < 4; ++t) {
                bf16x8 bfrag = __builtin_bit_cast(
                    bf16x8, *(const uint4*)(bbase + (c * 4 + t) * 1024 + lane * 16));
                acc[t] = __builtin_amdgcn_mfma_f32_32x32x16_bf16(afrag, bfrag, acc[t], 0, 0, 0);
            }
        }
        __builtin_amdgcn_s_setprio(0);

        // ONE barrier per tap: ensures (a) all waves done reading buf[cur] before it
        // is overwritten at k+2, (b) stage of tap k+1 complete (vmcnt(0) drain).
        __syncthreads();
        cur ^= 1;
    }

    // ---- epilogue: store pre-BN, accumulate channel sums ----
    // C/D layout (32x32): col = lane&31, row = (reg&3) + 8*(reg>>2) + 4*(lane>>5)
#pragma unroll
    for (int t = 0; t < 4; ++t) {
#pragma unroll
        for (int r = 0; r < 16; ++r) {
            int row_local = (r & 3) + 8 * (r >> 2) + 4 * hj;
            size_t grow = (size_t)blockIdx.x * 256 + wave * 32 + row_local;
            if (grow < N_PTS) {
                if (OUT_BF16)
                    ((__hip_bfloat16*)out_any)[grow * COUT + (t * 32 + m)] =
                        (__hip_bfloat16)acc[t][r];
                else
                    ((float*)out_any)[grow * COUT + (t * 32 + m)] = acc[t][r];
            }
        }
    }

    float s[4], q[4];
#pragma unroll
    for (int t = 0; t < 4; ++t) {
        s[t] = 0.0f; q[t] = 0.0f;
#pragma unroll
        for (int r = 0; r < 16; ++r) {
            float v = acc[t][r];
            s[t] += v;
            q[t] += v * v;
        }
        s[t] += __shfl_xor(s[t], 32, 64);
        q[t] += __shfl_xor(q[t], 32, 64);
    }

    // reuse smem (all LDS reads finished before the last barrier in the tap loop)
    float* lsum = (float*)smem;           // [8][128]
    float* lsq = (float*)(smem + 4096);   // [8][128]
    if (hj == 0) {
#pragma unroll
        for (int t = 0; t < 4; ++t) {
            lsum[wave * 128 + t * 32 + m] = s[t];
            lsq[wave * 128 + t * 32 + m] = q[t];
        }
    }
    __syncthreads();
    if (tid < 128) {
        float ts = 0.0f, tq = 0.0f;
#pragma unroll
        for (int w = 0; w < 8; ++w) {
            ts += lsum[w * 128 + tid];
            tq += lsq[w * 128 + tid];
        }
        atomicAdd(&gsum[tid], ts);
        atomicAdd(&gsumsq[tid], tq);
    }
}

__global__ void finalize_scales_kernel(const float* __restrict__ gsum,
                                       const float* __restrict__ gsumsq,
                                       const float* __restrict__ gamma,
                                       const float* __restrict__ beta,
                                       float* __restrict__ ab) {
    int c = threadIdx.x;  // 0..127
    const float inv_n = 1.0f / (float)N_PTS;
    float mean = gsum[c] * inv_n;
    float var = gsumsq[c] * inv_n - mean * mean;
    float a = gamma[c] * rsqrtf(var + EPS_BN);
    ab[c] = a;
    ab[128 + c] = beta[c] - mean * a;
}

// Path A: read pre-BN bf16 from ws, write fp32 out. 8 elems/thread.
__global__ __launch_bounds__(256) void bn_lrelu_bf16_kernel(
    const __hip_bfloat16* __restrict__ pre, float* __restrict__ out,
    const float* __restrict__ ab) {
    size_t i = ((size_t)blockIdx.x * 256 + threadIdx.x) * 8;
    int c0 = (int)(i & (COUT - 1));
    uint4 v = *(const uint4*)(pre + i);
    unsigned int u[4] = {v.x, v.y, v.z, v.w};
    float o[8];
#pragma unroll
    for (int w = 0; w < 4; ++w) {
        float x0 = __uint_as_float((u[w] & 0xffffu) << 16);
        float x1 = __uint_as_float((u[w] >> 16) << 16);
        int c = c0 + 2 * w;
        float y0 = fmaf(ab[c], x0, ab[128 + c]);
        float y1 = fmaf(ab[c + 1], x1, ab[128 + c + 1]);
        o[2 * w] = (y0 > 0.0f) ? y0 : LEAK * y0;
        o[2 * w + 1] = (y1 > 0.0f) ? y1 : LEAK * y1;
    }
    *(float4*)(out + i) = make_float4(o[0], o[1], o[2], o[3]);
    *(float4*)(out + i + 4) = make_float4(o[4], o[5], o[6], o[7]);
}

// Path B: in-place fp32 BN + LeakyReLU, 4 elems/thread.
__global__ __launch_bounds__(256) void bn_lrelu_f32_kernel(
    float* __restrict__ out, const float* __restrict__ ab) {
    size_t i = ((size_t)blockIdx.x * 256 + threadIdx.x) * 4;
    int c = (int)(i & (COUT - 1));
    float4 v = *(const float4*)(out + i);
    v.x = fmaf(ab[c], v.x, ab[128 + c]);
    v.y = fmaf(ab[c + 1], v.y, ab[128 + c + 1]);
    v.z = fmaf(ab[c + 2], v.z, ab[128 + c + 2]);
    v.w = fmaf(ab[c + 3], v.w, ab[128 + c + 3]);
    v.x = (v.x > 0.0f) ? v.x : LEAK * v.x;
    v.y = (v.y > 0.0f) ? v.y : LEAK * v.y;
    v.z = (v.z > 0.0f) ? v.z : LEAK * v.z;
    v.w = (v.w > 0.0f) ? v.w : LEAK * v.w;
    *(float4*)(out + i) = v;
}

extern "C" void kernel_launch(void* const* d_in, const int* in_sizes, int n_in,
                              void* d_out, int out_size, void* d_ws, size_t ws_size,
                              hipStream_t stream) {
    const float* feats = (const float*)d_in[0];
    const float* W = (const float*)d_in[1];
    // d_in[2] = bias: cancels exactly under BatchNorm (out - mean removes per-channel constants)
    const float* gamma = (const float*)d_in[3];
    const float* beta = (const float*)d_in[4];
    const int* neigh = (const int*)d_in[5];
    float* out = (float*)d_out;

    char* ws = (char*)d_ws;
    __hip_bfloat16* packw = (__hip_bfloat16*)ws;
    float* gsum = (float*)(ws + SUMS_OFF);
    float* gsumsq = (float*)(ws + SUMSQ_OFF);
    float* ab = (float*)(ws + AB_OFF);

    const int gemm_grid = (N_PTS + 255) / 256;  // 1563 (tail rows guarded)

    hipLaunchKernelGGL(zero_sums_kernel, dim3(1), dim3(256), 0, stream, gsum);
    hipLaunchKernelGGL(pack_w_kernel, dim3(288), dim3(64), 0, stream, W, packw);

    if (ws_size >= WS_NEED_A) {
        __hip_bfloat16* featsb = (__hip_bfloat16*)(ws + FEATSB_OFF);
        __hip_bfloat16* prebn = (__hip_bfloat16*)(ws + PREBN_OFF);
        hipLaunchKernelGGL(convert_feats_kernel, dim3(25000), dim3(256), 0, stream, feats, featsb);
        hipLaunchKernelGGL((spconv_gemm_kernel<true, true>), dim3(gemm_grid), dim3(512), 0,
                           stream, (const void*)featsb, packw, neigh, (void*)prebn, gsum, gsumsq);
        hipLaunchKernelGGL(finalize_scales_kernel, dim3(1), dim3(128), 0, stream,
                           gsum, gsumsq, gamma, beta, ab);
        hipLaunchKernelGGL(bn_lrelu_bf16_kernel, dim3(25000), dim3(256), 0, stream,
                           prebn, out, ab);
    } else {
        hipLaunchKernelGGL((spconv_gemm_kernel<false, false>), dim3(gemm_grid), dim3(512), 0,
                           stream, (const void*)feats, packw, neigh, (void*)out, gsum, gsumsq);
        hipLaunchKernelGGL(finalize_scales_kernel, dim3(1), dim3(128), 0, stream,
                           gsum, gsumsq, gamma, beta, ab);
        hipLaunchKernelGGL(bn_lrelu_f32_kernel, dim3(50000), dim3(256), 0, stream, out, ab);
    }
}